// Round 1
// baseline (3312.880 us; speedup 1.0000x reference)
//
#include <hip/hip_runtime.h>
#include <cstdint>
#include <cstddef>

#define N_NODES 40000
#define N_EDGES 640000
#define N_GRAPH 256
#define HDIM 128
#define NLAYERS 5
#define ZDIM 257

// ---------------- embed gather: x[n,:] = embed[atoms[n],:] ----------------
__global__ void k_embed(const int* __restrict__ atoms, const float* __restrict__ embed,
                        float* __restrict__ x) {
    int i = blockIdx.x * blockDim.x + threadIdx.x;   // float4 index
    if (i >= N_NODES * 32) return;
    int n = i >> 5, c = i & 31;
    int a = atoms[n];
    ((float4*)x)[(size_t)n * 32 + c] = ((const float4*)embed)[(size_t)a * 32 + c];
}

// ---------------- edge_attr = ||pos[src]-pos[dst]|| ----------------
__global__ void k_ea(const int* __restrict__ ei, const float* __restrict__ pos,
                     float* __restrict__ ea) {
    int e = blockIdx.x * blockDim.x + threadIdx.x;
    if (e >= N_EDGES) return;
    int s = ei[e], d = ei[N_EDGES + e];
    float dx = pos[3 * s] - pos[3 * d];
    float dy = pos[3 * s + 1] - pos[3 * d + 1];
    float dz = pos[3 * s + 2] - pos[3 * d + 2];
    ea[e] = sqrtf(dx * dx + dy * dy + dz * dz);
}

// ---------------- pack layer weights: Wp[k][p*128+h] ----------------
// p=0: Wf[h][k]  p=1: Wf[h][128+k]  p=2: Ws[h][k]  p=3: Ws[h][128+k]
// plus edge-scalar columns wfe[h]=Wf[h][256], wse[h]=Ws[h][256]
__global__ void k_pack(const float* __restrict__ wf, const float* __restrict__ ws,
                       float* __restrict__ Wp, float* __restrict__ wfe,
                       float* __restrict__ wse) {
    int i = blockIdx.x * blockDim.x + threadIdx.x;
    if (i < 128 * 512) {
        int k = i >> 9, c = i & 511;
        int p = c >> 7, h = c & 127;
        const float* W = (p < 2) ? wf : ws;
        int col = (p & 1) * 128 + k;
        Wp[i] = W[h * ZDIM + col];
    } else {
        int j = i - 128 * 512;
        if (j < 128) wfe[j] = wf[j * ZDIM + 256];
        else if (j < 256) wse[j - 128] = ws[(j - 128) * ZDIM + 256];
    }
}

// ---------------- node GEMM: P[n, 512] = x[n,128] @ Wp[128,512] ----------------
__launch_bounds__(256, 2)
__global__ void k_gemm(const float* __restrict__ x, const float* __restrict__ Wp,
                       float* __restrict__ P) {
    __shared__ float xs[32][128];
    int row0 = blockIdx.x * 32;
    int tid = threadIdx.x;
    const float4* xsrc = (const float4*)(x + (size_t)row0 * 128);
    float4* xdst = (float4*)&xs[0][0];
    for (int i = tid; i < 32 * 32; i += 256) xdst[i] = xsrc[i];
    __syncthreads();
    int tc = tid & 63, tr = tid >> 6;
    float acc[8][8];
#pragma unroll
    for (int r = 0; r < 8; ++r)
#pragma unroll
        for (int c = 0; c < 8; ++c) acc[r][c] = 0.f;
    const float* wbase = Wp + tc * 8;
    for (int k = 0; k < 128; ++k) {
        float xv[8];
#pragma unroll
        for (int r = 0; r < 8; ++r) xv[r] = xs[tr * 8 + r][k];
        float4 w0 = *(const float4*)(wbase + k * 512);
        float4 w1 = *(const float4*)(wbase + k * 512 + 4);
        float wv[8] = {w0.x, w0.y, w0.z, w0.w, w1.x, w1.y, w1.z, w1.w};
#pragma unroll
        for (int r = 0; r < 8; ++r)
#pragma unroll
            for (int c = 0; c < 8; ++c) acc[r][c] = fmaf(xv[r], wv[c], acc[r][c]);
    }
#pragma unroll
    for (int r = 0; r < 8; ++r) {
        float* dst = P + (size_t)(row0 + tr * 8 + r) * 512 + tc * 8;
        *(float4*)dst = make_float4(acc[r][0], acc[r][1], acc[r][2], acc[r][3]);
        *(float4*)(dst + 4) = make_float4(acc[r][4], acc[r][5], acc[r][6], acc[r][7]);
    }
}

// ---------------- edge kernel: one wave per edge, atomic residual into x ----------------
__launch_bounds__(256)
__global__ void k_edge(const float* __restrict__ P, const float* __restrict__ ea,
                       const float* __restrict__ wfe, const float* __restrict__ wse,
                       const float* __restrict__ bf, const float* __restrict__ bs,
                       const int* __restrict__ ei, float* __restrict__ x) {
    int e = (blockIdx.x * 256 + threadIdx.x) >> 6;
    if (e >= N_EDGES) return;
    int lane = threadIdx.x & 63;
    int s = ei[e], d = ei[N_EDGES + e];
    float eav = ea[e];
    const float2* Pd = (const float2*)(P + (size_t)d * 512);
    const float2* Ps = (const float2*)(P + (size_t)s * 512);
    float2 fi = Pd[lane];            // part0: dst through Wf_i
    float2 fj = Ps[64 + lane];       // part1: src through Wf_j
    float2 si = Pd[128 + lane];      // part2: dst through Ws_i
    float2 sj = Ps[192 + lane];      // part3: src through Ws_j
    float2 wf = ((const float2*)wfe)[lane];
    float2 wsv = ((const float2*)wse)[lane];
    float2 bfv = ((const float2*)bf)[lane];
    float2 bsv = ((const float2*)bs)[lane];
    float g0 = fi.x + fj.x + eav * wf.x + bfv.x;
    float g1 = fi.y + fj.y + eav * wf.y + bfv.y;
    float c0 = si.x + sj.x + eav * wsv.x + bsv.x;
    float c1 = si.y + sj.y + eav * wsv.y + bsv.y;
    float sg0 = 1.f / (1.f + __expf(-g0));
    float sg1 = 1.f / (1.f + __expf(-g1));
    float sp0 = fmaxf(c0, 0.f) + log1pf(__expf(-fabsf(c0)));
    float sp1 = fmaxf(c1, 0.f) + log1pf(__expf(-fabsf(c1)));
    float m0 = sg0 * sp0;
    float m1 = sg1 * sp1;
    float* xd = x + (size_t)d * HDIM + 2 * lane;
    unsafeAtomicAdd(xd, m0);
    unsafeAtomicAdd(xd + 1, m1);
}

// ---------------- mean-pool accumulate ----------------
__global__ void k_pool(const float* __restrict__ x, const int* __restrict__ batch,
                       float* __restrict__ gsum, float* __restrict__ gcnt) {
    int n = (blockIdx.x * 256 + threadIdx.x) >> 6;
    if (n >= N_NODES) return;
    int lane = threadIdx.x & 63;
    int b = batch[n];
    float2 v = ((const float2*)(x + (size_t)n * HDIM))[lane];
    float* gd = gsum + (size_t)b * HDIM + 2 * lane;
    unsafeAtomicAdd(gd, v.x);
    unsafeAtomicAdd(gd + 1, v.y);
    if (lane == 0) unsafeAtomicAdd(gcnt + b, 1.0f);
}

// ---------------- FC head: one block per graph ----------------
__launch_bounds__(128)
__global__ void k_fc(const float* __restrict__ gsum, const float* __restrict__ gcnt,
                     const float* __restrict__ fc_w, const float* __restrict__ fc_b,
                     const float* __restrict__ out_w, const float* __restrict__ out_b,
                     float* __restrict__ out) {
    int g = blockIdx.x;
    int h = threadIdx.x;
    __shared__ float gin[128];
    __shared__ float gout[128];
    float cnt = fmaxf(gcnt[g], 1.0f);
    gin[h] = gsum[(size_t)g * HDIM + h] / cnt;
    __syncthreads();
    for (int l = 0; l < 3; ++l) {
        const float* W = fc_w + (size_t)l * HDIM * HDIM + (size_t)h * HDIM;
        float s = fc_b[l * HDIM + h];
#pragma unroll 4
        for (int k = 0; k < HDIM; k += 4) {
            float4 w4 = *(const float4*)(W + k);
            s += gin[k] * w4.x + gin[k + 1] * w4.y + gin[k + 2] * w4.z + gin[k + 3] * w4.w;
        }
        __syncthreads();
        gout[h] = s;
        __syncthreads();
        gin[h] = gout[h];
        __syncthreads();
    }
    float v = gin[h] * out_w[h];
    gout[h] = v;
    __syncthreads();
    if (h < 64) gout[h] += gout[h + 64];
    __syncthreads();
    if (h == 0) {
        float s = 0.f;
        for (int i = 0; i < 64; ++i) s += gout[i];
        out[g] = s + out_b[0];
    }
}

extern "C" void kernel_launch(void* const* d_in, const int* in_sizes, int n_in,
                              void* d_out, int out_size, void* d_ws, size_t ws_size,
                              hipStream_t stream) {
    const int* atoms = (const int*)d_in[0];
    const float* pos = (const float*)d_in[1];
    const int* ei = (const int*)d_in[2];
    const int* batch = (const int*)d_in[3];
    const float* embed = (const float*)d_in[4];
    const float* lin_f_w = (const float*)d_in[5];
    const float* lin_f_b = (const float*)d_in[6];
    const float* lin_s_w = (const float*)d_in[7];
    const float* lin_s_b = (const float*)d_in[8];
    const float* fc_w = (const float*)d_in[9];
    const float* fc_b = (const float*)d_in[10];
    const float* out_w = (const float*)d_in[11];
    const float* out_b = (const float*)d_in[12];
    float* out = (float*)d_out;

    char* ws = (char*)d_ws;
    size_t off = 0;
    auto alloc = [&](size_t bytes) -> void* {
        void* p = ws + off;
        off += (bytes + 255) & ~(size_t)255;
        return p;
    };
    float* x    = (float*)alloc((size_t)N_NODES * HDIM * 4);
    float* P    = (float*)alloc((size_t)N_NODES * 512 * 4);
    float* ea   = (float*)alloc((size_t)N_EDGES * 4);
    float* Wp   = (float*)alloc((size_t)128 * 512 * 4);
    float* wfe  = (float*)alloc(128 * 4);
    float* wse  = (float*)alloc(128 * 4);
    float* gsum = (float*)alloc((size_t)N_GRAPH * HDIM * 4);
    float* gcnt = (float*)alloc((size_t)N_GRAPH * 4);

    hipMemsetAsync(gsum, 0, (size_t)N_GRAPH * HDIM * 4, stream);
    hipMemsetAsync(gcnt, 0, (size_t)N_GRAPH * 4, stream);

    k_embed<<<(N_NODES * 32 + 255) / 256, 256, 0, stream>>>(atoms, embed, x);
    k_ea<<<(N_EDGES + 255) / 256, 256, 0, stream>>>(ei, pos, ea);

    for (int l = 0; l < NLAYERS; ++l) {
        k_pack<<<257, 256, 0, stream>>>(lin_f_w + (size_t)l * HDIM * ZDIM,
                                        lin_s_w + (size_t)l * HDIM * ZDIM,
                                        Wp, wfe, wse);
        k_gemm<<<N_NODES / 32, 256, 0, stream>>>(x, Wp, P);
        k_edge<<<N_EDGES / 4, 256, 0, stream>>>(P, ea, wfe, wse,
                                                lin_f_b + (size_t)l * HDIM,
                                                lin_s_b + (size_t)l * HDIM,
                                                ei, x);
    }

    k_pool<<<N_NODES / 4, 256, 0, stream>>>(x, batch, gsum, gcnt);
    k_fc<<<N_GRAPH, 128, 0, stream>>>(gsum, gcnt, fc_w, fc_b, out_w, out_b, out);
}

// Round 2
// 995.723 us; speedup vs baseline: 3.3271x; 3.3271x over previous
//
#include <hip/hip_runtime.h>
#include <cstdint>
#include <cstddef>

#define N_NODES 40000
#define N_EDGES 640000
#define N_GRAPH 256
#define HDIM 128
#define NLAYERS 5
#define ZDIM 257

typedef unsigned short ushort8_t __attribute__((ext_vector_type(8)));

static __device__ __forceinline__ float bf2f(unsigned short h) {
    return __uint_as_float((unsigned)h << 16);
}
static __device__ __forceinline__ unsigned short f2bf(float f) {
    unsigned u = __float_as_uint(f);
    unsigned r = u + 0x7fffu + ((u >> 16) & 1u);
    return (unsigned short)(r >> 16);
}

// ---------------- embed gather: x[n,:] = embed[atoms[n],:] ----------------
__global__ void k_embed(const int* __restrict__ atoms, const float* __restrict__ embed,
                        float* __restrict__ x) {
    int i = blockIdx.x * blockDim.x + threadIdx.x;   // float4 index
    if (i >= N_NODES * 32) return;
    int n = i >> 5, c = i & 31;
    int a = atoms[n];
    ((float4*)x)[(size_t)n * 32 + c] = ((const float4*)embed)[(size_t)a * 32 + c];
}

// ---------------- degree histogram ----------------
__global__ void k_hist(const int* __restrict__ ei, int* __restrict__ deg) {
    int e = blockIdx.x * 256 + threadIdx.x;
    if (e >= N_EDGES) return;
    atomicAdd(&deg[ei[N_EDGES + e]], 1);
}

// ---------------- exclusive scan over deg[40000] -> rowptr[40001], cursor ----------------
__launch_bounds__(1024)
__global__ void k_scan(const int* __restrict__ deg, int* __restrict__ rowptr,
                       int* __restrict__ cursor) {
    __shared__ int buf[1024];
    __shared__ int carry_s;
    int tid = threadIdx.x;
    if (tid == 0) carry_s = 0;
    __syncthreads();
    for (int chunk = 0; chunk < 40; ++chunk) {
        int i = chunk * 1024 + tid;
        int v = (i < N_NODES) ? deg[i] : 0;
        buf[tid] = v;
        __syncthreads();
        for (int off = 1; off < 1024; off <<= 1) {
            int t = (tid >= off) ? buf[tid - off] : 0;
            __syncthreads();
            buf[tid] += t;
            __syncthreads();
        }
        int incl = buf[tid];
        int base = carry_s;
        if (i < N_NODES) {
            int excl = base + incl - v;
            rowptr[i] = excl;
            cursor[i] = excl;
        }
        __syncthreads();
        if (tid == 1023) carry_s = base + incl;
        __syncthreads();
    }
    if (tid == 0) rowptr[N_NODES] = carry_s;
}

// ---------------- scatter edges into CSR (by dst), computing ea inline ----------------
__global__ void k_scatter(const int* __restrict__ ei, const float* __restrict__ pos,
                          int* __restrict__ cursor, int2* __restrict__ csr) {
    int e = blockIdx.x * 256 + threadIdx.x;
    if (e >= N_EDGES) return;
    int s = ei[e], d = ei[N_EDGES + e];
    float dx = pos[3 * s] - pos[3 * d];
    float dy = pos[3 * s + 1] - pos[3 * d + 1];
    float dz = pos[3 * s + 2] - pos[3 * d + 2];
    float ea = sqrtf(dx * dx + dy * dy + dz * dz);
    int p = atomicAdd(&cursor[d], 1);
    csr[p] = make_int2(s, __float_as_int(ea));
}

// ---------------- pack layer weights into interleaved-column layout ----------------
// Output P element layout per node (512 bf16):
//   c in [0,256): src block.  l=c>>2, t=c&3, ch=2l+(t&1). t<2 -> Wf[ch][128+k], else Ws[ch][128+k]
//   c in [256,512): dst block. same decode with cc=c-256. t<2 -> Wf[ch][k] (+bf), else Ws[ch][k] (+bs)
__global__ void k_pack(const float* __restrict__ wf, const float* __restrict__ ws,
                       float* __restrict__ Wp, float* __restrict__ wfe,
                       float* __restrict__ wse) {
    int i = blockIdx.x * 256 + threadIdx.x;
    if (i < 128 * 512) {
        int k = i >> 9, c = i & 511;
        int blk = c >> 8;        // 0 = src block, 1 = dst block
        int cc = c & 255;
        int t = cc & 3;
        int ch = 2 * (cc >> 2) + (t & 1);
        const float* W = (t < 2) ? wf : ws;
        int col = blk ? k : (128 + k);
        Wp[i] = W[ch * ZDIM + col];
    } else if (i < 128 * 512 + 256) {
        int j = i - 128 * 512;
        if (j < 128) wfe[j] = wf[j * ZDIM + 256];
        else wse[j - 128] = ws[(j - 128) * ZDIM + 256];
    }
}

// ---------------- node GEMM: P[n, 512] = x[n,128] @ Wp[128,512], +bias, ->bf16 ----------------
__launch_bounds__(256, 2)
__global__ void k_gemm(const float* __restrict__ x, const float* __restrict__ Wp,
                       const float* __restrict__ bf, const float* __restrict__ bs,
                       unsigned short* __restrict__ P) {
    __shared__ float xs[32][128];
    int row0 = blockIdx.x * 32;
    int tid = threadIdx.x;
    const float4* xsrc = (const float4*)(x + (size_t)row0 * 128);
    float4* xdst = (float4*)&xs[0][0];
    for (int i = tid; i < 32 * 32; i += 256) xdst[i] = xsrc[i];
    __syncthreads();
    int tc = tid & 63, tr = tid >> 6;
    float acc[8][8];
#pragma unroll
    for (int r = 0; r < 8; ++r)
#pragma unroll
        for (int c = 0; c < 8; ++c) acc[r][c] = 0.f;
    const float* wbase = Wp + tc * 8;
    for (int k = 0; k < 128; ++k) {
        float xv[8];
#pragma unroll
        for (int r = 0; r < 8; ++r) xv[r] = xs[tr * 8 + r][k];
        float4 w0 = *(const float4*)(wbase + k * 512);
        float4 w1 = *(const float4*)(wbase + k * 512 + 4);
        float wv[8] = {w0.x, w0.y, w0.z, w0.w, w1.x, w1.y, w1.z, w1.w};
#pragma unroll
        for (int r = 0; r < 8; ++r)
#pragma unroll
            for (int c = 0; c < 8; ++c) acc[r][c] = fmaf(xv[r], wv[c], acc[r][c]);
    }
    // per-column bias (folded into dst block)
    float badd[8];
#pragma unroll
    for (int i = 0; i < 8; ++i) {
        int c = tc * 8 + i;
        if (c < 256) badd[i] = 0.f;
        else {
            int cc = c - 256;
            int t = cc & 3;
            int ch = 2 * (cc >> 2) + (t & 1);
            badd[i] = (t < 2) ? bf[ch] : bs[ch];
        }
    }
#pragma unroll
    for (int r = 0; r < 8; ++r) {
        ushort8_t v;
#pragma unroll
        for (int i = 0; i < 8; ++i) v[i] = f2bf(acc[r][i] + badd[i]);
        *(ushort8_t*)(P + (size_t)(row0 + tr * 8 + r) * 512 + tc * 8) = v;
    }
}

// ---------------- CSR edge kernel: one wave per dst node ----------------
__launch_bounds__(256)
__global__ void k_edge_csr(const unsigned short* __restrict__ P,
                           const float* __restrict__ wfe, const float* __restrict__ wse,
                           const int* __restrict__ rowptr, const int2* __restrict__ csr,
                           float* __restrict__ x) {
    int node = blockIdx.x * 4 + (threadIdx.x >> 6);
    if (node >= N_NODES) return;
    int lane = threadIdx.x & 63;
    int beg = rowptr[node], end = rowptr[node + 1];
    // dst block: ushort idx 256 + 4*lane : {P0[2l], P0[2l+1], P2[2l], P2[2l+1]} (+biases)
    ushort4 dv = *(const ushort4*)(P + (size_t)node * 512 + 256 + 4 * lane);
    float fi0 = bf2f(dv.x), fi1 = bf2f(dv.y);
    float si0 = bf2f(dv.z), si1 = bf2f(dv.w);
    float2 wf = ((const float2*)wfe)[lane];
    float2 wsv = ((const float2*)wse)[lane];
    float acc0 = 0.f, acc1 = 0.f;
    if (beg < end) {
        int2 nx = csr[beg];
        for (int e = beg; e < end; ++e) {
            int2 cur = nx;
            if (e + 1 < end) nx = csr[e + 1];
            int s = __builtin_amdgcn_readfirstlane(cur.x);
            float eav = __uint_as_float(__builtin_amdgcn_readfirstlane((unsigned)cur.y));
            // src block: one contiguous 512B gather, 8B per lane
            ushort4 sv = *(const ushort4*)(P + (size_t)s * 512 + 4 * lane);
            float g0 = fi0 + bf2f(sv.x) + eav * wf.x;
            float g1 = fi1 + bf2f(sv.y) + eav * wf.y;
            float c0 = si0 + bf2f(sv.z) + eav * wsv.x;
            float c1 = si1 + bf2f(sv.w) + eav * wsv.y;
            const float LOG2E = 1.44269504f, LN2 = 0.69314718f;
            float sg0 = __builtin_amdgcn_rcpf(1.f + __builtin_amdgcn_exp2f(-g0 * LOG2E));
            float sg1 = __builtin_amdgcn_rcpf(1.f + __builtin_amdgcn_exp2f(-g1 * LOG2E));
            float a0 = fabsf(c0), a1 = fabsf(c1);
            float l0 = __builtin_amdgcn_logf(1.f + __builtin_amdgcn_exp2f(-a0 * LOG2E)) * LN2;
            float l1 = __builtin_amdgcn_logf(1.f + __builtin_amdgcn_exp2f(-a1 * LOG2E)) * LN2;
            float sp0 = fmaxf(c0, 0.f) + l0;
            float sp1 = fmaxf(c1, 0.f) + l1;
            acc0 += sg0 * sp0;
            acc1 += sg1 * sp1;
        }
    }
    float2* xd = (float2*)(x + (size_t)node * 128) + lane;
    float2 xv = *xd;
    xv.x += acc0;
    xv.y += acc1;
    *xd = xv;
}

// ---------------- mean-pool accumulate ----------------
__global__ void k_pool(const float* __restrict__ x, const int* __restrict__ batch,
                       float* __restrict__ gsum, float* __restrict__ gcnt) {
    int n = (blockIdx.x * 256 + threadIdx.x) >> 6;
    if (n >= N_NODES) return;
    int lane = threadIdx.x & 63;
    int b = batch[n];
    float2 v = ((const float2*)(x + (size_t)n * HDIM))[lane];
    float* gd = gsum + (size_t)b * HDIM + 2 * lane;
    unsafeAtomicAdd(gd, v.x);
    unsafeAtomicAdd(gd + 1, v.y);
    if (lane == 0) unsafeAtomicAdd(gcnt + b, 1.0f);
}

// ---------------- FC head: one block per graph ----------------
__launch_bounds__(128)
__global__ void k_fc(const float* __restrict__ gsum, const float* __restrict__ gcnt,
                     const float* __restrict__ fc_w, const float* __restrict__ fc_b,
                     const float* __restrict__ out_w, const float* __restrict__ out_b,
                     float* __restrict__ out) {
    int g = blockIdx.x;
    int h = threadIdx.x;
    __shared__ float gin[128];
    __shared__ float gout[128];
    float cnt = fmaxf(gcnt[g], 1.0f);
    gin[h] = gsum[(size_t)g * HDIM + h] / cnt;
    __syncthreads();
    for (int l = 0; l < 3; ++l) {
        const float* W = fc_w + (size_t)l * HDIM * HDIM + (size_t)h * HDIM;
        float s = fc_b[l * HDIM + h];
#pragma unroll 4
        for (int k = 0; k < HDIM; k += 4) {
            float4 w4 = *(const float4*)(W + k);
            s += gin[k] * w4.x + gin[k + 1] * w4.y + gin[k + 2] * w4.z + gin[k + 3] * w4.w;
        }
        __syncthreads();
        gout[h] = s;
        __syncthreads();
        gin[h] = gout[h];
        __syncthreads();
    }
    float v = gin[h] * out_w[h];
    gout[h] = v;
    __syncthreads();
    if (h < 64) gout[h] += gout[h + 64];
    __syncthreads();
    if (h == 0) {
        float s = 0.f;
        for (int i = 0; i < 64; ++i) s += gout[i];
        out[g] = s + out_b[0];
    }
}

extern "C" void kernel_launch(void* const* d_in, const int* in_sizes, int n_in,
                              void* d_out, int out_size, void* d_ws, size_t ws_size,
                              hipStream_t stream) {
    const int* atoms = (const int*)d_in[0];
    const float* pos = (const float*)d_in[1];
    const int* ei = (const int*)d_in[2];
    const int* batch = (const int*)d_in[3];
    const float* embed = (const float*)d_in[4];
    const float* lin_f_w = (const float*)d_in[5];
    const float* lin_f_b = (const float*)d_in[6];
    const float* lin_s_w = (const float*)d_in[7];
    const float* lin_s_b = (const float*)d_in[8];
    const float* fc_w = (const float*)d_in[9];
    const float* fc_b = (const float*)d_in[10];
    const float* out_w = (const float*)d_in[11];
    const float* out_b = (const float*)d_in[12];
    float* out = (float*)d_out;

    char* ws = (char*)d_ws;
    size_t off = 0;
    auto alloc = [&](size_t bytes) -> void* {
        void* p = ws + off;
        off += (bytes + 255) & ~(size_t)255;
        return p;
    };
    float* x            = (float*)alloc((size_t)N_NODES * HDIM * 4);
    unsigned short* P   = (unsigned short*)alloc((size_t)N_NODES * 512 * 2);
    float* Wp           = (float*)alloc((size_t)128 * 512 * 4);
    float* wfe          = (float*)alloc(128 * 4);
    float* wse          = (float*)alloc(128 * 4);
    float* gsum         = (float*)alloc((size_t)N_GRAPH * HDIM * 4);
    float* gcnt         = (float*)alloc((size_t)N_GRAPH * 4);
    int* deg            = (int*)alloc((size_t)N_NODES * 4);
    int* rowptr         = (int*)alloc((size_t)(N_NODES + 1) * 4);
    int* cursor         = (int*)alloc((size_t)N_NODES * 4);
    int2* csr           = (int2*)alloc((size_t)N_EDGES * 8);

    hipMemsetAsync(gsum, 0, (size_t)N_GRAPH * HDIM * 4, stream);
    hipMemsetAsync(gcnt, 0, (size_t)N_GRAPH * 4, stream);
    hipMemsetAsync(deg, 0, (size_t)N_NODES * 4, stream);

    k_embed<<<(N_NODES * 32 + 255) / 256, 256, 0, stream>>>(atoms, embed, x);
    k_hist<<<(N_EDGES + 255) / 256, 256, 0, stream>>>(ei, deg);
    k_scan<<<1, 1024, 0, stream>>>(deg, rowptr, cursor);
    k_scatter<<<(N_EDGES + 255) / 256, 256, 0, stream>>>(ei, pos, cursor, csr);

    for (int l = 0; l < NLAYERS; ++l) {
        k_pack<<<257, 256, 0, stream>>>(lin_f_w + (size_t)l * HDIM * ZDIM,
                                        lin_s_w + (size_t)l * HDIM * ZDIM,
                                        Wp, wfe, wse);
        k_gemm<<<N_NODES / 32, 256, 0, stream>>>(x, Wp,
                                                 lin_f_b + (size_t)l * HDIM,
                                                 lin_s_b + (size_t)l * HDIM, P);
        k_edge_csr<<<N_NODES / 4, 256, 0, stream>>>(P, wfe, wse, rowptr, csr, x);
    }

    k_pool<<<N_NODES / 4, 256, 0, stream>>>(x, batch, gsum, gcnt);
    k_fc<<<N_GRAPH, 128, 0, stream>>>(gsum, gcnt, fc_w, fc_b, out_w, out_b, out);
}

// Round 3
// 720.884 us; speedup vs baseline: 4.5956x; 1.3813x over previous
//
#include <hip/hip_runtime.h>
#include <cstdint>
#include <cstddef>

#define N_NODES 40000
#define N_EDGES 640000
#define N_GRAPH 256
#define HDIM 128
#define NLAYERS 5
#define ZDIM 257

typedef unsigned short ushort8_t __attribute__((ext_vector_type(8)));
typedef short short8 __attribute__((ext_vector_type(8)));
typedef float float4v __attribute__((ext_vector_type(4)));

static __device__ __forceinline__ float bf2f(unsigned short h) {
    return __uint_as_float((unsigned)h << 16);
}
static __device__ __forceinline__ unsigned short f2bf(float f) {
    unsigned u = __float_as_uint(f);
    unsigned r = u + 0x7fffu + ((u >> 16) & 1u);
    return (unsigned short)(r >> 16);
}

// ---------------- embed gather: x[n,:] = embed[atoms[n],:] ----------------
__global__ void k_embed(const int* __restrict__ atoms, const float* __restrict__ embed,
                        float* __restrict__ x) {
    int i = blockIdx.x * blockDim.x + threadIdx.x;   // float4 index
    if (i >= N_NODES * 32) return;
    int n = i >> 5, c = i & 31;
    int a = atoms[n];
    ((float4*)x)[(size_t)n * 32 + c] = ((const float4*)embed)[(size_t)a * 32 + c];
}

// ---------------- degree histogram ----------------
__global__ void k_hist(const int* __restrict__ ei, int* __restrict__ deg) {
    int e = blockIdx.x * 256 + threadIdx.x;
    if (e >= N_EDGES) return;
    atomicAdd(&deg[ei[N_EDGES + e]], 1);
}

// ---------------- exclusive scan over deg[40000] -> rowptr[40001], cursor ----------------
__launch_bounds__(1024)
__global__ void k_scan(const int* __restrict__ deg, int* __restrict__ rowptr,
                       int* __restrict__ cursor) {
    __shared__ int buf[1024];
    __shared__ int carry_s;
    int tid = threadIdx.x;
    if (tid == 0) carry_s = 0;
    __syncthreads();
    for (int chunk = 0; chunk < 40; ++chunk) {
        int i = chunk * 1024 + tid;
        int v = (i < N_NODES) ? deg[i] : 0;
        buf[tid] = v;
        __syncthreads();
        for (int off = 1; off < 1024; off <<= 1) {
            int t = (tid >= off) ? buf[tid - off] : 0;
            __syncthreads();
            buf[tid] += t;
            __syncthreads();
        }
        int incl = buf[tid];
        int base = carry_s;
        if (i < N_NODES) {
            int excl = base + incl - v;
            rowptr[i] = excl;
            cursor[i] = excl;
        }
        __syncthreads();
        if (tid == 1023) carry_s = base + incl;
        __syncthreads();
    }
    if (tid == 0) rowptr[N_NODES] = carry_s;
}

// ---------------- scatter edges into CSR (by dst), computing ea inline ----------------
__global__ void k_scatter(const int* __restrict__ ei, const float* __restrict__ pos,
                          int* __restrict__ cursor, int2* __restrict__ csr) {
    int e = blockIdx.x * 256 + threadIdx.x;
    if (e >= N_EDGES) return;
    int s = ei[e], d = ei[N_EDGES + e];
    float dx = pos[3 * s] - pos[3 * d];
    float dy = pos[3 * s + 1] - pos[3 * d + 1];
    float dz = pos[3 * s + 2] - pos[3 * d + 2];
    float ea = sqrtf(dx * dx + dy * dy + dz * dz);
    int p = atomicAdd(&cursor[d], 1);
    csr[p] = make_int2(s, __float_as_int(ea));
}

// ---------------- graph boundaries from sorted batch ----------------
__global__ void k_gbound(const int* __restrict__ batch, int* __restrict__ gstart) {
    int g = blockIdx.x * 256 + threadIdx.x;
    if (g > N_GRAPH) return;
    if (g == N_GRAPH) { gstart[g] = N_NODES; return; }
    int lo = 0, hi = N_NODES;
    while (lo < hi) {
        int mid = (lo + hi) >> 1;
        if (batch[mid] < g) lo = mid + 1; else hi = mid;
    }
    gstart[g] = lo;
}

// ---------------- pack layer weights -> Wp_packed bf16 [n=512][k=128] ----------------
// n in [0,256): src block. t=n&3, ch=2*(n>>2)+(t&1). t<2 -> Wf[ch][128+k], else Ws[ch][128+k]
// n in [256,512): dst block. cc=n-256, same decode. t<2 -> Wf[ch][k], else Ws[ch][k]
__global__ void k_pack(const float* __restrict__ wf, const float* __restrict__ ws,
                       unsigned short* __restrict__ Wp, float* __restrict__ wfe,
                       float* __restrict__ wse) {
    int i = blockIdx.x * 256 + threadIdx.x;
    if (i < 512 * 128) {
        int n = i >> 7, k = i & 127;
        int blk = n >> 8;        // 0 = src block, 1 = dst block
        int cc = n & 255;
        int t = cc & 3;
        int ch = 2 * (cc >> 2) + (t & 1);
        const float* W = (t < 2) ? wf : ws;
        int col = blk ? k : (128 + k);
        Wp[i] = f2bf(W[ch * ZDIM + col]);
    } else if (i < 512 * 128 + 256) {
        int j = i - 512 * 128;
        if (j < 128) wfe[j] = wf[j * ZDIM + 256];
        else wse[j - 128] = ws[(j - 128) * ZDIM + 256];
    }
}

// ---------------- MFMA node GEMM: P[n,512] = bf16(x[n,128]) @ Wp[128,512] (+bias) ----------------
// grid (313, 2): blockIdx.x = row tile of 128 nodes, blockIdx.y = col half of 256.
// 512 threads = 8 waves (2 row x 4 col), each wave -> 64x64 output (4x4 frags of 16x16x32).
__launch_bounds__(512, 2)
__global__ void k_gemm(const float* __restrict__ x, const unsigned short* __restrict__ Wp,
                       const float* __restrict__ bf, const float* __restrict__ bs,
                       unsigned short* __restrict__ P) {
    __shared__ unsigned short smem[128 * 256];   // 64 KB; A tile uses first 32 KB
    unsigned short* A = smem;
    const int row0 = blockIdx.x * 128;
    const int colbase = blockIdx.y * 256;
    const int tid = threadIdx.x;

    // ---- stage A: x[row0..row0+128) f32 -> bf16 LDS, XOR-swizzled in 8-elem groups ----
    {
        int r = tid >> 2, q = tid & 3;           // row, 32-col quarter
        int grow = row0 + r;
        if (grow > N_NODES - 1) grow = N_NODES - 1;
        const float4* src = (const float4*)(x + (size_t)grow * 128 + q * 32);
        int h = r & 7;
#pragma unroll
        for (int i = 0; i < 4; ++i) {
            float4 a = src[2 * i];
            float4 b = src[2 * i + 1];
            ushort8_t v;
            v[0] = f2bf(a.x); v[1] = f2bf(a.y); v[2] = f2bf(a.z); v[3] = f2bf(a.w);
            v[4] = f2bf(b.x); v[5] = f2bf(b.y); v[6] = f2bf(b.z); v[7] = f2bf(b.w);
            int kg = 4 * q + i;                  // 8-elem k-group 0..15
            *(ushort8_t*)(A + r * 128 + ((kg ^ h) * 8)) = v;
        }
    }
    __syncthreads();

    const int wid = tid >> 6, lane = tid & 63;
    const int wr = wid >> 2, wc = wid & 3;       // 2 x 4 waves
    const int l16 = lane & 15, lg = lane >> 4;

    float4v acc[4][4];
#pragma unroll
    for (int i = 0; i < 4; ++i)
#pragma unroll
        for (int j = 0; j < 4; ++j) acc[i][j] = (float4v){0.f, 0.f, 0.f, 0.f};

#pragma unroll
    for (int ks = 0; ks < 4; ++ks) {             // K = 128 in steps of 32
        short8 af[4], bfr[4];
#pragma unroll
        for (int rf = 0; rf < 4; ++rf) {
            int row = wr * 64 + rf * 16 + l16;
            int kg = ks * 4 + lg;
            af[rf] = *(const short8*)(A + row * 128 + ((kg ^ (row & 7)) * 8));
        }
#pragma unroll
        for (int cf = 0; cf < 4; ++cf) {
            int n = colbase + wc * 64 + cf * 16 + l16;
            bfr[cf] = *(const short8*)(Wp + (size_t)n * 128 + ks * 32 + lg * 8);
        }
#pragma unroll
        for (int rf = 0; rf < 4; ++rf)
#pragma unroll
            for (int cf = 0; cf < 4; ++cf)
                acc[rf][cf] = __builtin_amdgcn_mfma_f32_16x16x32_bf16(
                    af[rf], bfr[cf], acc[rf][cf], 0, 0, 0);
    }

    // ---- bias for dst half (blockIdx.y == 1) ----
    float bias[4] = {0.f, 0.f, 0.f, 0.f};
    if (blockIdx.y == 1) {
#pragma unroll
        for (int cf = 0; cf < 4; ++cf) {
            int cc = wc * 64 + cf * 16 + l16;    // = n - 256
            int t = cc & 3;
            int ch = 2 * (cc >> 2) + (t & 1);
            bias[cf] = (t < 2) ? bf[ch] : bs[ch];
        }
    }

    __syncthreads();   // done with A tile
    // ---- stage output tile (128x256 bf16) to LDS for coalesced store ----
#pragma unroll
    for (int rf = 0; rf < 4; ++rf)
#pragma unroll
        for (int cf = 0; cf < 4; ++cf) {
            int col = wc * 64 + cf * 16 + l16;
#pragma unroll
            for (int r = 0; r < 4; ++r) {
                int row = wr * 64 + rf * 16 + lg * 4 + r;
                smem[row * 256 + col] = f2bf(acc[rf][cf][r] + bias[cf]);
            }
        }
    __syncthreads();
    // ---- coalesced store: thread t -> row t>>2, 64-col chunk (t&3) ----
    {
        int r = tid >> 2, q = tid & 3;
        int grow = row0 + r;
        if (grow < N_NODES) {
            const ushort8_t* s = (const ushort8_t*)(smem + r * 256 + q * 64);
            ushort8_t* d = (ushort8_t*)(P + (size_t)grow * 512 + colbase + q * 64);
#pragma unroll
            for (int i = 0; i < 8; ++i) d[i] = s[i];
        }
    }
}

// ---------------- CSR edge kernel: one wave per dst node ----------------
__launch_bounds__(256)
__global__ void k_edge_csr(const unsigned short* __restrict__ P,
                           const float* __restrict__ wfe, const float* __restrict__ wse,
                           const int* __restrict__ rowptr, const int2* __restrict__ csr,
                           float* __restrict__ x) {
    int node = blockIdx.x * 4 + (threadIdx.x >> 6);
    if (node >= N_NODES) return;
    int lane = threadIdx.x & 63;
    int beg = rowptr[node], end = rowptr[node + 1];
    ushort4 dv = *(const ushort4*)(P + (size_t)node * 512 + 256 + 4 * lane);
    float fi0 = bf2f(dv.x), fi1 = bf2f(dv.y);
    float si0 = bf2f(dv.z), si1 = bf2f(dv.w);
    float2 wf = ((const float2*)wfe)[lane];
    float2 wsv = ((const float2*)wse)[lane];
    float acc0 = 0.f, acc1 = 0.f;
    if (beg < end) {
        int2 nx = csr[beg];
        for (int e = beg; e < end; ++e) {
            int2 cur = nx;
            if (e + 1 < end) nx = csr[e + 1];
            int s = __builtin_amdgcn_readfirstlane(cur.x);
            float eav = __uint_as_float(__builtin_amdgcn_readfirstlane((unsigned)cur.y));
            ushort4 sv = *(const ushort4*)(P + (size_t)s * 512 + 4 * lane);
            float g0 = fi0 + bf2f(sv.x) + eav * wf.x;
            float g1 = fi1 + bf2f(sv.y) + eav * wf.y;
            float c0 = si0 + bf2f(sv.z) + eav * wsv.x;
            float c1 = si1 + bf2f(sv.w) + eav * wsv.y;
            const float LOG2E = 1.44269504f, LN2 = 0.69314718f;
            float sg0 = __builtin_amdgcn_rcpf(1.f + __builtin_amdgcn_exp2f(-g0 * LOG2E));
            float sg1 = __builtin_amdgcn_rcpf(1.f + __builtin_amdgcn_exp2f(-g1 * LOG2E));
            float a0 = fabsf(c0), a1 = fabsf(c1);
            float l0 = __builtin_amdgcn_logf(1.f + __builtin_amdgcn_exp2f(-a0 * LOG2E)) * LN2;
            float l1 = __builtin_amdgcn_logf(1.f + __builtin_amdgcn_exp2f(-a1 * LOG2E)) * LN2;
            float sp0 = fmaxf(c0, 0.f) + l0;
            float sp1 = fmaxf(c1, 0.f) + l1;
            acc0 += sg0 * sp0;
            acc1 += sg1 * sp1;
        }
    }
    float2* xd = (float2*)(x + (size_t)node * 128) + lane;
    float2 xv = *xd;
    xv.x += acc0;
    xv.y += acc1;
    *xd = xv;
}

// ---------------- fused mean-pool (segmented, no atomics) + FC head ----------------
__launch_bounds__(128)
__global__ void k_poolfc(const float* __restrict__ x, const int* __restrict__ gstart,
                         const float* __restrict__ fc_w, const float* __restrict__ fc_b,
                         const float* __restrict__ out_w, const float* __restrict__ out_b,
                         float* __restrict__ out) {
    int g = blockIdx.x;
    int h = threadIdx.x;
    int s = gstart[g], e = gstart[g + 1];
    float sum = 0.f;
    for (int n = s; n < e; ++n) sum += x[(size_t)n * HDIM + h];
    __shared__ float gin[128];
    __shared__ float gout[128];
    float cnt = fmaxf((float)(e - s), 1.0f);
    gin[h] = sum / cnt;
    __syncthreads();
    for (int l = 0; l < 3; ++l) {
        const float* W = fc_w + (size_t)l * HDIM * HDIM + (size_t)h * HDIM;
        float acc = fc_b[l * HDIM + h];
#pragma unroll 4
        for (int k = 0; k < HDIM; k += 4) {
            float4 w4 = *(const float4*)(W + k);
            acc += gin[k] * w4.x + gin[k + 1] * w4.y + gin[k + 2] * w4.z + gin[k + 3] * w4.w;
        }
        __syncthreads();
        gout[h] = acc;
        __syncthreads();
        gin[h] = gout[h];
        __syncthreads();
    }
    float v = gin[h] * out_w[h];
    gout[h] = v;
    __syncthreads();
    if (h < 64) gout[h] += gout[h + 64];
    __syncthreads();
    if (h == 0) {
        float acc = 0.f;
        for (int i = 0; i < 64; ++i) acc += gout[i];
        out[g] = acc + out_b[0];
    }
}

extern "C" void kernel_launch(void* const* d_in, const int* in_sizes, int n_in,
                              void* d_out, int out_size, void* d_ws, size_t ws_size,
                              hipStream_t stream) {
    const int* atoms = (const int*)d_in[0];
    const float* pos = (const float*)d_in[1];
    const int* ei = (const int*)d_in[2];
    const int* batch = (const int*)d_in[3];
    const float* embed = (const float*)d_in[4];
    const float* lin_f_w = (const float*)d_in[5];
    const float* lin_f_b = (const float*)d_in[6];
    const float* lin_s_w = (const float*)d_in[7];
    const float* lin_s_b = (const float*)d_in[8];
    const float* fc_w = (const float*)d_in[9];
    const float* fc_b = (const float*)d_in[10];
    const float* out_w = (const float*)d_in[11];
    const float* out_b = (const float*)d_in[12];
    float* out = (float*)d_out;

    char* ws = (char*)d_ws;
    size_t off = 0;
    auto alloc = [&](size_t bytes) -> void* {
        void* p = ws + off;
        off += (bytes + 255) & ~(size_t)255;
        return p;
    };
    float* x            = (float*)alloc((size_t)N_NODES * HDIM * 4);
    unsigned short* P   = (unsigned short*)alloc((size_t)N_NODES * 512 * 2);
    unsigned short* Wp  = (unsigned short*)alloc((size_t)512 * 128 * 2);
    float* wfe          = (float*)alloc(128 * 4);
    float* wse          = (float*)alloc(128 * 4);
    int* deg            = (int*)alloc((size_t)N_NODES * 4);
    int* rowptr         = (int*)alloc((size_t)(N_NODES + 1) * 4);
    int* cursor         = (int*)alloc((size_t)N_NODES * 4);
    int* gstart         = (int*)alloc((size_t)(N_GRAPH + 1) * 4);
    int2* csr           = (int2*)alloc((size_t)N_EDGES * 8);

    hipMemsetAsync(deg, 0, (size_t)N_NODES * 4, stream);

    k_embed<<<(N_NODES * 32 + 255) / 256, 256, 0, stream>>>(atoms, embed, x);
    k_hist<<<(N_EDGES + 255) / 256, 256, 0, stream>>>(ei, deg);
    k_scan<<<1, 1024, 0, stream>>>(deg, rowptr, cursor);
    k_scatter<<<(N_EDGES + 255) / 256, 256, 0, stream>>>(ei, pos, cursor, csr);
    k_gbound<<<2, 256, 0, stream>>>(batch, gstart);

    for (int l = 0; l < NLAYERS; ++l) {
        k_pack<<<257, 256, 0, stream>>>(lin_f_w + (size_t)l * HDIM * ZDIM,
                                        lin_s_w + (size_t)l * HDIM * ZDIM,
                                        Wp, wfe, wse);
        k_gemm<<<dim3(313, 2), 512, 0, stream>>>(x, Wp,
                                                 lin_f_b + (size_t)l * HDIM,
                                                 lin_s_b + (size_t)l * HDIM, P);
        k_edge_csr<<<N_NODES / 4, 256, 0, stream>>>(P, wfe, wse, rowptr, csr, x);
    }

    k_poolfc<<<N_GRAPH, 128, 0, stream>>>(x, gstart, fc_w, fc_b, out_w, out_b, out);
}

// Round 4
// 707.759 us; speedup vs baseline: 4.6808x; 1.0185x over previous
//
#include <hip/hip_runtime.h>
#include <cstdint>
#include <cstddef>

#define N_NODES 40000
#define N_EDGES 640000
#define N_GRAPH 256
#define HDIM 128
#define NLAYERS 5
#define ZDIM 257

typedef unsigned short ushort8_t __attribute__((ext_vector_type(8)));
typedef short short8 __attribute__((ext_vector_type(8)));
typedef float float4v __attribute__((ext_vector_type(4)));

static __device__ __forceinline__ float bf2f(unsigned short h) {
    return __uint_as_float((unsigned)h << 16);
}
static __device__ __forceinline__ unsigned short f2bf(float f) {
    unsigned u = __float_as_uint(f);
    unsigned r = u + 0x7fffu + ((u >> 16) & 1u);
    return (unsigned short)(r >> 16);
}

// ---------------- embed gather: x[n,:] = embed[atoms[n],:] ----------------
__global__ void k_embed(const int* __restrict__ atoms, const float* __restrict__ embed,
                        float* __restrict__ x) {
    int i = blockIdx.x * blockDim.x + threadIdx.x;   // float4 index
    if (i >= N_NODES * 32) return;
    int n = i >> 5, c = i & 31;
    int a = atoms[n];
    ((float4*)x)[(size_t)n * 32 + c] = ((const float4*)embed)[(size_t)a * 32 + c];
}

// ---------------- degree histogram ----------------
__global__ void k_hist(const int* __restrict__ ei, int* __restrict__ deg) {
    int e = blockIdx.x * 256 + threadIdx.x;
    if (e >= N_EDGES) return;
    atomicAdd(&deg[ei[N_EDGES + e]], 1);
}

// ---------------- exclusive scan over deg[40000] -> rowptr[40001], cursor ----------------
// Each thread owns 40 contiguous nodes; local prefix in registers; one LDS scan
// over the 1024 per-thread totals (10 barrier rounds total, vs 400 before).
__launch_bounds__(1024)
__global__ void k_scan(const int* __restrict__ deg, int* __restrict__ rowptr,
                       int* __restrict__ cursor) {
    __shared__ int ssum[1024];
    int tid = threadIdx.x;
    int base = tid * 40;                 // 40*1024 = 40960 >= 40000
    int vals[40];
    int s = 0;
#pragma unroll
    for (int i = 0; i < 40; ++i) {
        int idx = base + i;
        int v = (idx < N_NODES) ? deg[idx] : 0;
        vals[i] = s;                     // local exclusive prefix
        s += v;
    }
    ssum[tid] = s;
    __syncthreads();
    for (int off = 1; off < 1024; off <<= 1) {
        int t = (tid >= off) ? ssum[tid - off] : 0;
        __syncthreads();
        ssum[tid] += t;
        __syncthreads();
    }
    int excl = ssum[tid] - s;            // block-level exclusive prefix for this thread
#pragma unroll
    for (int i = 0; i < 40; ++i) {
        int idx = base + i;
        if (idx < N_NODES) {
            int e = excl + vals[i];
            rowptr[idx] = e;
            cursor[idx] = e;
        }
    }
    if (tid == 1023) rowptr[N_NODES] = ssum[1023];
}

// ---------------- scatter edges into CSR (by dst), computing ea inline ----------------
__global__ void k_scatter(const int* __restrict__ ei, const float* __restrict__ pos,
                          int* __restrict__ cursor, int2* __restrict__ csr) {
    int e = blockIdx.x * 256 + threadIdx.x;
    if (e >= N_EDGES) return;
    int s = ei[e], d = ei[N_EDGES + e];
    float dx = pos[3 * s] - pos[3 * d];
    float dy = pos[3 * s + 1] - pos[3 * d + 1];
    float dz = pos[3 * s + 2] - pos[3 * d + 2];
    float ea = sqrtf(dx * dx + dy * dy + dz * dz);
    int p = atomicAdd(&cursor[d], 1);
    csr[p] = make_int2(s, __float_as_int(ea));
}

// ---------------- graph boundaries from sorted batch ----------------
__global__ void k_gbound(const int* __restrict__ batch, int* __restrict__ gstart) {
    int g = blockIdx.x * 256 + threadIdx.x;
    if (g > N_GRAPH) return;
    if (g == N_GRAPH) { gstart[g] = N_NODES; return; }
    int lo = 0, hi = N_NODES;
    while (lo < hi) {
        int mid = (lo + hi) >> 1;
        if (batch[mid] < g) lo = mid + 1; else hi = mid;
    }
    gstart[g] = lo;
}

// ---------------- pack layer weights -> Wp_packed bf16 [n=512][k=128] ----------------
// n in [0,256): src block. t=n&3, ch=2*(n>>2)+(t&1). t<2 -> Wf[ch][128+k], else Ws[ch][128+k]
// n in [256,512): dst block. cc=n-256, same decode. t<2 -> Wf[ch][k], else Ws[ch][k]
__global__ void k_pack(const float* __restrict__ wf, const float* __restrict__ ws,
                       unsigned short* __restrict__ Wp, float* __restrict__ wfe,
                       float* __restrict__ wse) {
    int i = blockIdx.x * 256 + threadIdx.x;
    if (i < 512 * 128) {
        int n = i >> 7, k = i & 127;
        int blk = n >> 8;        // 0 = src block, 1 = dst block
        int cc = n & 255;
        int t = cc & 3;
        int ch = 2 * (cc >> 2) + (t & 1);
        const float* W = (t < 2) ? wf : ws;
        int col = blk ? k : (128 + k);
        Wp[i] = f2bf(W[ch * ZDIM + col]);
    } else if (i < 512 * 128 + 256) {
        int j = i - 512 * 128;
        if (j < 128) wfe[j] = wf[j * ZDIM + 256];
        else wse[j - 128] = ws[(j - 128) * ZDIM + 256];
    }
}

// ---------------- MFMA node GEMM: P[n,512] = bf16(x[n,128]) @ Wp[128,512] (+bias) ----------------
// grid (313, 2): blockIdx.x = row tile of 128 nodes, blockIdx.y = col half of 256.
// 512 threads = 8 waves (2 row x 4 col), each wave -> 64x64 output (4x4 frags of 16x16x32).
__launch_bounds__(512, 2)
__global__ void k_gemm(const float* __restrict__ x, const unsigned short* __restrict__ Wp,
                       const float* __restrict__ bf, const float* __restrict__ bs,
                       unsigned short* __restrict__ P) {
    __shared__ unsigned short smem[128 * 256];   // 64 KB; A tile uses first 32 KB
    unsigned short* A = smem;
    const int row0 = blockIdx.x * 128;
    const int colbase = blockIdx.y * 256;
    const int tid = threadIdx.x;

    // ---- stage A: x[row0..row0+128) f32 -> bf16 LDS, XOR-swizzled in 8-elem groups ----
    {
        int r = tid >> 2, q = tid & 3;           // row, 32-col quarter
        int grow = row0 + r;
        if (grow > N_NODES - 1) grow = N_NODES - 1;
        const float4* src = (const float4*)(x + (size_t)grow * 128 + q * 32);
        int h = r & 7;
#pragma unroll
        for (int i = 0; i < 4; ++i) {
            float4 a = src[2 * i];
            float4 b = src[2 * i + 1];
            ushort8_t v;
            v[0] = f2bf(a.x); v[1] = f2bf(a.y); v[2] = f2bf(a.z); v[3] = f2bf(a.w);
            v[4] = f2bf(b.x); v[5] = f2bf(b.y); v[6] = f2bf(b.z); v[7] = f2bf(b.w);
            int kg = 4 * q + i;                  // 8-elem k-group 0..15
            *(ushort8_t*)(A + r * 128 + ((kg ^ h) * 8)) = v;
        }
    }
    __syncthreads();

    const int wid = tid >> 6, lane = tid & 63;
    const int wr = wid >> 2, wc = wid & 3;       // 2 x 4 waves
    const int l16 = lane & 15, lg = lane >> 4;

    float4v acc[4][4];
#pragma unroll
    for (int i = 0; i < 4; ++i)
#pragma unroll
        for (int j = 0; j < 4; ++j) acc[i][j] = (float4v){0.f, 0.f, 0.f, 0.f};

#pragma unroll
    for (int ks = 0; ks < 4; ++ks) {             // K = 128 in steps of 32
        short8 af[4], bfr[4];
#pragma unroll
        for (int rf = 0; rf < 4; ++rf) {
            int row = wr * 64 + rf * 16 + l16;
            int kg = ks * 4 + lg;
            af[rf] = *(const short8*)(A + row * 128 + ((kg ^ (row & 7)) * 8));
        }
#pragma unroll
        for (int cf = 0; cf < 4; ++cf) {
            int n = colbase + wc * 64 + cf * 16 + l16;
            bfr[cf] = *(const short8*)(Wp + (size_t)n * 128 + ks * 32 + lg * 8);
        }
#pragma unroll
        for (int rf = 0; rf < 4; ++rf)
#pragma unroll
            for (int cf = 0; cf < 4; ++cf)
                acc[rf][cf] = __builtin_amdgcn_mfma_f32_16x16x32_bf16(
                    af[rf], bfr[cf], acc[rf][cf], 0, 0, 0);
    }

    // ---- bias for dst half (blockIdx.y == 1) ----
    float bias[4] = {0.f, 0.f, 0.f, 0.f};
    if (blockIdx.y == 1) {
#pragma unroll
        for (int cf = 0; cf < 4; ++cf) {
            int cc = wc * 64 + cf * 16 + l16;    // = n - 256
            int t = cc & 3;
            int ch = 2 * (cc >> 2) + (t & 1);
            bias[cf] = (t < 2) ? bf[ch] : bs[ch];
        }
    }

    __syncthreads();   // done with A tile
    // ---- stage output tile (128x256 bf16) to LDS for coalesced store ----
#pragma unroll
    for (int rf = 0; rf < 4; ++rf)
#pragma unroll
        for (int cf = 0; cf < 4; ++cf) {
            int col = wc * 64 + cf * 16 + l16;
#pragma unroll
            for (int r = 0; r < 4; ++r) {
                int row = wr * 64 + rf * 16 + lg * 4 + r;
                smem[row * 256 + col] = f2bf(acc[rf][cf][r] + bias[cf]);
            }
        }
    __syncthreads();
    // ---- coalesced store: thread t -> row t>>2, 64-col chunk (t&3) ----
    {
        int r = tid >> 2, q = tid & 3;
        int grow = row0 + r;
        if (grow < N_NODES) {
            const ushort8_t* s = (const ushort8_t*)(smem + r * 256 + q * 64);
            ushort8_t* d = (ushort8_t*)(P + (size_t)grow * 512 + colbase + q * 64);
#pragma unroll
            for (int i = 0; i < 8; ++i) d[i] = s[i];
        }
    }
}

// ---------------- CSR edge kernel: one wave per dst node ----------------
__launch_bounds__(256)
__global__ void k_edge_csr(const unsigned short* __restrict__ P,
                           const float* __restrict__ wfe, const float* __restrict__ wse,
                           const int* __restrict__ rowptr, const int2* __restrict__ csr,
                           float* __restrict__ x) {
    int node = blockIdx.x * 4 + (threadIdx.x >> 6);
    if (node >= N_NODES) return;
    int lane = threadIdx.x & 63;
    int beg = rowptr[node], end = rowptr[node + 1];
    ushort4 dv = *(const ushort4*)(P + (size_t)node * 512 + 256 + 4 * lane);
    float fi0 = bf2f(dv.x), fi1 = bf2f(dv.y);
    float si0 = bf2f(dv.z), si1 = bf2f(dv.w);
    float2 wf = ((const float2*)wfe)[lane];
    float2 wsv = ((const float2*)wse)[lane];
    float acc0 = 0.f, acc1 = 0.f;
    if (beg < end) {
        int2 nx = csr[beg];
        for (int e = beg; e < end; ++e) {
            int2 cur = nx;
            if (e + 1 < end) nx = csr[e + 1];
            int s = __builtin_amdgcn_readfirstlane(cur.x);
            float eav = __uint_as_float(__builtin_amdgcn_readfirstlane((unsigned)cur.y));
            ushort4 sv = *(const ushort4*)(P + (size_t)s * 512 + 4 * lane);
            float g0 = fi0 + bf2f(sv.x) + eav * wf.x;
            float g1 = fi1 + bf2f(sv.y) + eav * wf.y;
            float c0 = si0 + bf2f(sv.z) + eav * wsv.x;
            float c1 = si1 + bf2f(sv.w) + eav * wsv.y;
            const float LOG2E = 1.44269504f, LN2 = 0.69314718f;
            float sg0 = __builtin_amdgcn_rcpf(1.f + __builtin_amdgcn_exp2f(-g0 * LOG2E));
            float sg1 = __builtin_amdgcn_rcpf(1.f + __builtin_amdgcn_exp2f(-g1 * LOG2E));
            float a0 = fabsf(c0), a1 = fabsf(c1);
            float l0 = __builtin_amdgcn_logf(1.f + __builtin_amdgcn_exp2f(-a0 * LOG2E)) * LN2;
            float l1 = __builtin_amdgcn_logf(1.f + __builtin_amdgcn_exp2f(-a1 * LOG2E)) * LN2;
            float sp0 = fmaxf(c0, 0.f) + l0;
            float sp1 = fmaxf(c1, 0.f) + l1;
            acc0 += sg0 * sp0;
            acc1 += sg1 * sp1;
        }
    }
    float2* xd = (float2*)(x + (size_t)node * 128) + lane;
    float2 xv = *xd;
    xv.x += acc0;
    xv.y += acc1;
    *xd = xv;
}

// ---------------- fused mean-pool (segmented, no atomics) + FC head ----------------
__launch_bounds__(128)
__global__ void k_poolfc(const float* __restrict__ x, const int* __restrict__ gstart,
                         const float* __restrict__ fc_w, const float* __restrict__ fc_b,
                         const float* __restrict__ out_w, const float* __restrict__ out_b,
                         float* __restrict__ out) {
    int g = blockIdx.x;
    int h = threadIdx.x;
    int s = gstart[g], e = gstart[g + 1];
    float sum = 0.f;
    for (int n = s; n < e; ++n) sum += x[(size_t)n * HDIM + h];
    __shared__ float gin[128];
    __shared__ float gout[128];
    float cnt = fmaxf((float)(e - s), 1.0f);
    gin[h] = sum / cnt;
    __syncthreads();
    for (int l = 0; l < 3; ++l) {
        const float* W = fc_w + (size_t)l * HDIM * HDIM + (size_t)h * HDIM;
        float acc = fc_b[l * HDIM + h];
#pragma unroll 4
        for (int k = 0; k < HDIM; k += 4) {
            float4 w4 = *(const float4*)(W + k);
            acc += gin[k] * w4.x + gin[k + 1] * w4.y + gin[k + 2] * w4.z + gin[k + 3] * w4.w;
        }
        __syncthreads();
        gout[h] = acc;
        __syncthreads();
        gin[h] = gout[h];
        __syncthreads();
    }
    float v = gin[h] * out_w[h];
    gout[h] = v;
    __syncthreads();
    if (h < 64) gout[h] += gout[h + 64];
    __syncthreads();
    if (h == 0) {
        float acc = 0.f;
        for (int i = 0; i < 64; ++i) acc += gout[i];
        out[g] = acc + out_b[0];
    }
}

extern "C" void kernel_launch(void* const* d_in, const int* in_sizes, int n_in,
                              void* d_out, int out_size, void* d_ws, size_t ws_size,
                              hipStream_t stream) {
    const int* atoms = (const int*)d_in[0];
    const float* pos = (const float*)d_in[1];
    const int* ei = (const int*)d_in[2];
    const int* batch = (const int*)d_in[3];
    const float* embed = (const float*)d_in[4];
    const float* lin_f_w = (const float*)d_in[5];
    const float* lin_f_b = (const float*)d_in[6];
    const float* lin_s_w = (const float*)d_in[7];
    const float* lin_s_b = (const float*)d_in[8];
    const float* fc_w = (const float*)d_in[9];
    const float* fc_b = (const float*)d_in[10];
    const float* out_w = (const float*)d_in[11];
    const float* out_b = (const float*)d_in[12];
    float* out = (float*)d_out;

    char* ws = (char*)d_ws;
    size_t off = 0;
    auto alloc = [&](size_t bytes) -> void* {
        void* p = ws + off;
        off += (bytes + 255) & ~(size_t)255;
        return p;
    };
    float* x            = (float*)alloc((size_t)N_NODES * HDIM * 4);
    unsigned short* P   = (unsigned short*)alloc((size_t)N_NODES * 512 * 2);
    unsigned short* Wp  = (unsigned short*)alloc((size_t)512 * 128 * 2);
    float* wfe          = (float*)alloc(128 * 4);
    float* wse          = (float*)alloc(128 * 4);
    int* deg            = (int*)alloc((size_t)N_NODES * 4);
    int* rowptr         = (int*)alloc((size_t)(N_NODES + 1) * 4);
    int* cursor         = (int*)alloc((size_t)N_NODES * 4);
    int* gstart         = (int*)alloc((size_t)(N_GRAPH + 1) * 4);
    int2* csr           = (int2*)alloc((size_t)N_EDGES * 8);

    hipMemsetAsync(deg, 0, (size_t)N_NODES * 4, stream);

    k_embed<<<(N_NODES * 32 + 255) / 256, 256, 0, stream>>>(atoms, embed, x);
    k_hist<<<(N_EDGES + 255) / 256, 256, 0, stream>>>(ei, deg);
    k_scan<<<1, 1024, 0, stream>>>(deg, rowptr, cursor);
    k_scatter<<<(N_EDGES + 255) / 256, 256, 0, stream>>>(ei, pos, cursor, csr);
    k_gbound<<<2, 256, 0, stream>>>(batch, gstart);

    for (int l = 0; l < NLAYERS; ++l) {
        k_pack<<<257, 256, 0, stream>>>(lin_f_w + (size_t)l * HDIM * ZDIM,
                                        lin_s_w + (size_t)l * HDIM * ZDIM,
                                        Wp, wfe, wse);
        k_gemm<<<dim3(313, 2), 512, 0, stream>>>(x, Wp,
                                                 lin_f_b + (size_t)l * HDIM,
                                                 lin_s_b + (size_t)l * HDIM, P);
        k_edge_csr<<<N_NODES / 4, 256, 0, stream>>>(P, wfe, wse, rowptr, csr, x);
    }

    k_poolfc<<<N_GRAPH, 128, 0, stream>>>(x, gstart, fc_w, fc_b, out_w, out_b, out);
}

// Round 5
// 661.099 us; speedup vs baseline: 5.0112x; 1.0706x over previous
//
#include <hip/hip_runtime.h>
#include <cstdint>
#include <cstddef>

#define N_NODES 40000
#define N_EDGES 640000
#define N_GRAPH 256
#define HDIM 128
#define NLAYERS 5
#define ZDIM 257

typedef unsigned short ushort8_t __attribute__((ext_vector_type(8)));
typedef short short8 __attribute__((ext_vector_type(8)));
typedef float float4v __attribute__((ext_vector_type(4)));

static __device__ __forceinline__ float bf2f(unsigned short h) {
    return __uint_as_float((unsigned)h << 16);
}
static __device__ __forceinline__ unsigned short f2bf(float f) {
    unsigned u = __float_as_uint(f);
    unsigned r = u + 0x7fffu + ((u >> 16) & 1u);
    return (unsigned short)(r >> 16);
}

// ---------------- embed gather: x[n,:] = embed[atoms[n],:] ----------------
__global__ void k_embed(const int* __restrict__ atoms, const float* __restrict__ embed,
                        float* __restrict__ x) {
    int i = blockIdx.x * blockDim.x + threadIdx.x;   // float4 index
    if (i >= N_NODES * 32) return;
    int n = i >> 5, c = i & 31;
    int a = atoms[n];
    ((float4*)x)[(size_t)n * 32 + c] = ((const float4*)embed)[(size_t)a * 32 + c];
}

// ---------------- degree histogram ----------------
__global__ void k_hist(const int* __restrict__ ei, int* __restrict__ deg) {
    int e = blockIdx.x * 256 + threadIdx.x;
    if (e >= N_EDGES) return;
    atomicAdd(&deg[ei[N_EDGES + e]], 1);
}

// ---------------- exclusive scan over deg[40000] -> rowptr[40001], cursor ----------------
// Thread-serial ownership: 40 nodes/thread in registers, one 10-round LDS scan.
__launch_bounds__(1024)
__global__ void k_scan(const int* __restrict__ deg, int* __restrict__ rowptr,
                       int* __restrict__ cursor) {
    __shared__ int ssum[1024];
    int tid = threadIdx.x;
    int base = tid * 40;                 // 40*1024 = 40960 >= 40000
    int vals[40];
    int s = 0;
#pragma unroll
    for (int i = 0; i < 40; ++i) {
        int idx = base + i;
        int v = (idx < N_NODES) ? deg[idx] : 0;
        vals[i] = s;                     // local exclusive prefix
        s += v;
    }
    ssum[tid] = s;
    __syncthreads();
    for (int off = 1; off < 1024; off <<= 1) {
        int t = (tid >= off) ? ssum[tid - off] : 0;
        __syncthreads();
        ssum[tid] += t;
        __syncthreads();
    }
    int excl = ssum[tid] - s;            // block-level exclusive prefix for this thread
#pragma unroll
    for (int i = 0; i < 40; ++i) {
        int idx = base + i;
        if (idx < N_NODES) {
            int e = excl + vals[i];
            rowptr[idx] = e;
            cursor[idx] = e;
        }
    }
    if (tid == 1023) rowptr[N_NODES] = ssum[1023];
}

// ---------------- scatter edges into CSR (by dst), computing ea inline ----------------
__global__ void k_scatter(const int* __restrict__ ei, const float* __restrict__ pos,
                          int* __restrict__ cursor, int2* __restrict__ csr) {
    int e = blockIdx.x * 256 + threadIdx.x;
    if (e >= N_EDGES) return;
    int s = ei[e], d = ei[N_EDGES + e];
    float dx = pos[3 * s] - pos[3 * d];
    float dy = pos[3 * s + 1] - pos[3 * d + 1];
    float dz = pos[3 * s + 2] - pos[3 * d + 2];
    float ea = sqrtf(dx * dx + dy * dy + dz * dz);
    int p = atomicAdd(&cursor[d], 1);
    csr[p] = make_int2(s, __float_as_int(ea));
}

// ---------------- graph boundaries from sorted batch ----------------
__global__ void k_gbound(const int* __restrict__ batch, int* __restrict__ gstart) {
    int g = blockIdx.x * 256 + threadIdx.x;
    if (g > N_GRAPH) return;
    if (g == N_GRAPH) { gstart[g] = N_NODES; return; }
    int lo = 0, hi = N_NODES;
    while (lo < hi) {
        int mid = (lo + hi) >> 1;
        if (batch[mid] < g) lo = mid + 1; else hi = mid;
    }
    gstart[g] = lo;
}

// ---------------- pack ALL 5 layers' weights -> Wp bf16 [l][n=512][k=128] ----------------
// n in [0,256): src block. t=n&3, ch=2*(n>>2)+(t&1). t<2 -> Wf[ch][128+k], else Ws[ch][128+k]
// n in [256,512): dst block. cc=n-256, same decode. t<2 -> Wf[ch][k], else Ws[ch][k]
__global__ void k_pack(const float* __restrict__ lin_f_w, const float* __restrict__ lin_s_w,
                       unsigned short* __restrict__ Wp, float* __restrict__ wfe,
                       float* __restrict__ wse) {
    int l = blockIdx.y;
    const float* wf = lin_f_w + (size_t)l * HDIM * ZDIM;
    const float* ws = lin_s_w + (size_t)l * HDIM * ZDIM;
    unsigned short* Wpl = Wp + (size_t)l * 512 * 128;
    int i = blockIdx.x * 256 + threadIdx.x;
    if (i < 512 * 128) {
        int n = i >> 7, k = i & 127;
        int blk = n >> 8;        // 0 = src block, 1 = dst block
        int cc = n & 255;
        int t = cc & 3;
        int ch = 2 * (cc >> 2) + (t & 1);
        const float* W = (t < 2) ? wf : ws;
        int col = blk ? k : (128 + k);
        Wpl[i] = f2bf(W[ch * ZDIM + col]);
    } else if (i < 512 * 128 + 256) {
        int j = i - 512 * 128;
        if (j < 128) wfe[l * 128 + j] = wf[j * ZDIM + 256];
        else wse[l * 128 + (j - 128)] = ws[(j - 128) * ZDIM + 256];
    }
}

// ---------------- MFMA node GEMM: P[n,512] = bf16(x[n,128]) @ Wp[128,512] (+bias) ----------------
// grid (625, 2): 64-row tiles (40000 = 625*64 exact), col half of 256.
// 512 threads = 8 waves, wave w -> cols [w*32, w*32+32) x rows 0..63 = 4x2 frags of 16x16x32.
// LDS 32 KB (A tile = first 16 KB, reused by 32 KB output stage) -> 3+ blocks/CU.
__launch_bounds__(512, 6)
__global__ void k_gemm(const float* __restrict__ x, const unsigned short* __restrict__ Wp,
                       const float* __restrict__ bf, const float* __restrict__ bs,
                       unsigned short* __restrict__ P) {
    __shared__ unsigned short smem[64 * 256];    // 32 KB
    unsigned short* A = smem;                    // A tile: 64 rows x 128 k (16 KB)
    const int row0 = blockIdx.x * 64;
    const int colbase = blockIdx.y * 256;
    const int tid = threadIdx.x;

    // ---- stage A: x[row0..row0+64) f32 -> bf16 LDS, XOR-swizzled in 8-elem k-groups ----
    {
        int r = tid >> 3, sub = tid & 7;         // row, 16-col sixteenth
        const float4* src = (const float4*)(x + (size_t)(row0 + r) * 128 + sub * 16);
        float4 a = src[0], b = src[1], c = src[2], d = src[3];
        ushort8_t v0, v1;
        v0[0] = f2bf(a.x); v0[1] = f2bf(a.y); v0[2] = f2bf(a.z); v0[3] = f2bf(a.w);
        v0[4] = f2bf(b.x); v0[5] = f2bf(b.y); v0[6] = f2bf(b.z); v0[7] = f2bf(b.w);
        v1[0] = f2bf(c.x); v1[1] = f2bf(c.y); v1[2] = f2bf(c.z); v1[3] = f2bf(c.w);
        v1[4] = f2bf(d.x); v1[5] = f2bf(d.y); v1[6] = f2bf(d.z); v1[7] = f2bf(d.w);
        int h = r & 7;
        *(ushort8_t*)(A + r * 128 + (((sub * 2) ^ h) * 8)) = v0;
        *(ushort8_t*)(A + r * 128 + (((sub * 2 + 1) ^ h) * 8)) = v1;
    }
    __syncthreads();

    const int wid = tid >> 6, lane = tid & 63;
    const int l16 = lane & 15, lg = lane >> 4;

    float4v acc[4][2];
#pragma unroll
    for (int i = 0; i < 4; ++i)
#pragma unroll
        for (int j = 0; j < 2; ++j) acc[i][j] = (float4v){0.f, 0.f, 0.f, 0.f};

#pragma unroll
    for (int ks = 0; ks < 4; ++ks) {             // K = 128 in steps of 32
        short8 af[4], bfr[2];
#pragma unroll
        for (int rf = 0; rf < 4; ++rf) {
            int row = rf * 16 + l16;
            int kg = ks * 4 + lg;
            af[rf] = *(const short8*)(A + row * 128 + ((kg ^ (row & 7)) * 8));
        }
#pragma unroll
        for (int cf = 0; cf < 2; ++cf) {
            int n = colbase + wid * 32 + cf * 16 + l16;
            bfr[cf] = *(const short8*)(Wp + (size_t)n * 128 + ks * 32 + lg * 8);
        }
#pragma unroll
        for (int rf = 0; rf < 4; ++rf)
#pragma unroll
            for (int cf = 0; cf < 2; ++cf)
                acc[rf][cf] = __builtin_amdgcn_mfma_f32_16x16x32_bf16(
                    af[rf], bfr[cf], acc[rf][cf], 0, 0, 0);
    }

    // ---- bias for dst half (blockIdx.y == 1) ----
    float bias[2] = {0.f, 0.f};
    if (blockIdx.y == 1) {
#pragma unroll
        for (int cf = 0; cf < 2; ++cf) {
            int cc = wid * 32 + cf * 16 + l16;   // = n - 256
            int t = cc & 3;
            int ch = 2 * (cc >> 2) + (t & 1);
            bias[cf] = (t < 2) ? bf[ch] : bs[ch];
        }
    }

    __syncthreads();   // A tile fully consumed
    // ---- stage output tile (64x256 bf16) to LDS for coalesced store ----
#pragma unroll
    for (int rf = 0; rf < 4; ++rf)
#pragma unroll
        for (int cf = 0; cf < 2; ++cf) {
            int col = wid * 32 + cf * 16 + l16;
#pragma unroll
            for (int r = 0; r < 4; ++r) {
                int row = rf * 16 + lg * 4 + r;
                smem[row * 256 + col] = f2bf(acc[rf][cf][r] + bias[cf]);
            }
        }
    __syncthreads();
    // ---- coalesced store: thread t -> row t>>3, 32-col chunk (t&7) ----
    {
        int r = tid >> 3, ch = tid & 7;
        const ushort8_t* s = (const ushort8_t*)(smem + r * 256 + ch * 32);
        ushort8_t* d = (ushort8_t*)(P + (size_t)(row0 + r) * 512 + colbase + ch * 32);
#pragma unroll
        for (int i = 0; i < 4; ++i) d[i] = s[i];
    }
}

// ---------------- CSR edge kernel: one wave per dst node, 2 edges in flight ----------------
__launch_bounds__(256)
__global__ void k_edge_csr(const unsigned short* __restrict__ P,
                           const float* __restrict__ wfe, const float* __restrict__ wse,
                           const int* __restrict__ rowptr, const int2* __restrict__ csr,
                           float* __restrict__ x) {
    int node = blockIdx.x * 4 + (threadIdx.x >> 6);
    if (node >= N_NODES) return;
    int lane = threadIdx.x & 63;
    int beg = rowptr[node], end = rowptr[node + 1];
    ushort4 dv = *(const ushort4*)(P + (size_t)node * 512 + 256 + 4 * lane);
    float fi0 = bf2f(dv.x), fi1 = bf2f(dv.y);
    float si0 = bf2f(dv.z), si1 = bf2f(dv.w);
    float2 wf = ((const float2*)wfe)[lane];
    float2 wsv = ((const float2*)wse)[lane];
    float acc0 = 0.f, acc1 = 0.f;
    const float LOG2E = 1.44269504f, LN2 = 0.69314718f;

    auto edge_math = [&](ushort4 sv, float eav) {
        float g0 = fi0 + bf2f(sv.x) + eav * wf.x;
        float g1 = fi1 + bf2f(sv.y) + eav * wf.y;
        float c0 = si0 + bf2f(sv.z) + eav * wsv.x;
        float c1 = si1 + bf2f(sv.w) + eav * wsv.y;
        float sg0 = __builtin_amdgcn_rcpf(1.f + __builtin_amdgcn_exp2f(-g0 * LOG2E));
        float sg1 = __builtin_amdgcn_rcpf(1.f + __builtin_amdgcn_exp2f(-g1 * LOG2E));
        float a0 = fabsf(c0), a1 = fabsf(c1);
        float l0 = __builtin_amdgcn_logf(1.f + __builtin_amdgcn_exp2f(-a0 * LOG2E)) * LN2;
        float l1 = __builtin_amdgcn_logf(1.f + __builtin_amdgcn_exp2f(-a1 * LOG2E)) * LN2;
        float sp0 = fmaxf(c0, 0.f) + l0;
        float sp1 = fmaxf(c1, 0.f) + l1;
        acc0 += sg0 * sp0;
        acc1 += sg1 * sp1;
    };

    int e = beg;
    for (; e + 2 <= end; e += 2) {
        int2 c0 = csr[e];
        int2 c1 = csr[e + 1];
        int s0 = __builtin_amdgcn_readfirstlane(c0.x);
        float ea0 = __uint_as_float(__builtin_amdgcn_readfirstlane((unsigned)c0.y));
        int s1 = __builtin_amdgcn_readfirstlane(c1.x);
        float ea1 = __uint_as_float(__builtin_amdgcn_readfirstlane((unsigned)c1.y));
        ushort4 sv0 = *(const ushort4*)(P + (size_t)s0 * 512 + 4 * lane);
        ushort4 sv1 = *(const ushort4*)(P + (size_t)s1 * 512 + 4 * lane);
        edge_math(sv0, ea0);
        edge_math(sv1, ea1);
    }
    if (e < end) {
        int2 c0 = csr[e];
        int s0 = __builtin_amdgcn_readfirstlane(c0.x);
        float ea0 = __uint_as_float(__builtin_amdgcn_readfirstlane((unsigned)c0.y));
        ushort4 sv0 = *(const ushort4*)(P + (size_t)s0 * 512 + 4 * lane);
        edge_math(sv0, ea0);
    }

    float2* xd = (float2*)(x + (size_t)node * 128) + lane;
    float2 xv = *xd;
    xv.x += acc0;
    xv.y += acc1;
    *xd = xv;
}

// ---------------- fused mean-pool (segmented, no atomics) + FC head ----------------
__launch_bounds__(128)
__global__ void k_poolfc(const float* __restrict__ x, const int* __restrict__ gstart,
                         const float* __restrict__ fc_w, const float* __restrict__ fc_b,
                         const float* __restrict__ out_w, const float* __restrict__ out_b,
                         float* __restrict__ out) {
    int g = blockIdx.x;
    int h = threadIdx.x;
    int s = gstart[g], e = gstart[g + 1];
    float sum = 0.f;
    for (int n = s; n < e; ++n) sum += x[(size_t)n * HDIM + h];
    __shared__ float gin[128];
    __shared__ float gout[128];
    float cnt = fmaxf((float)(e - s), 1.0f);
    gin[h] = sum / cnt;
    __syncthreads();
    for (int l = 0; l < 3; ++l) {
        const float* W = fc_w + (size_t)l * HDIM * HDIM + (size_t)h * HDIM;
        float acc = fc_b[l * HDIM + h];
#pragma unroll 4
        for (int k = 0; k < HDIM; k += 4) {
            float4 w4 = *(const float4*)(W + k);
            acc += gin[k] * w4.x + gin[k + 1] * w4.y + gin[k + 2] * w4.z + gin[k + 3] * w4.w;
        }
        __syncthreads();
        gout[h] = acc;
        __syncthreads();
        gin[h] = gout[h];
        __syncthreads();
    }
    float v = gin[h] * out_w[h];
    gout[h] = v;
    __syncthreads();
    if (h < 64) gout[h] += gout[h + 64];
    __syncthreads();
    if (h == 0) {
        float acc = 0.f;
        for (int i = 0; i < 64; ++i) acc += gout[i];
        out[g] = acc + out_b[0];
    }
}

extern "C" void kernel_launch(void* const* d_in, const int* in_sizes, int n_in,
                              void* d_out, int out_size, void* d_ws, size_t ws_size,
                              hipStream_t stream) {
    const int* atoms = (const int*)d_in[0];
    const float* pos = (const float*)d_in[1];
    const int* ei = (const int*)d_in[2];
    const int* batch = (const int*)d_in[3];
    const float* embed = (const float*)d_in[4];
    const float* lin_f_w = (const float*)d_in[5];
    const float* lin_f_b = (const float*)d_in[6];
    const float* lin_s_w = (const float*)d_in[7];
    const float* lin_s_b = (const float*)d_in[8];
    const float* fc_w = (const float*)d_in[9];
    const float* fc_b = (const float*)d_in[10];
    const float* out_w = (const float*)d_in[11];
    const float* out_b = (const float*)d_in[12];
    float* out = (float*)d_out;

    char* ws = (char*)d_ws;
    size_t off = 0;
    auto alloc = [&](size_t bytes) -> void* {
        void* p = ws + off;
        off += (bytes + 255) & ~(size_t)255;
        return p;
    };
    float* x            = (float*)alloc((size_t)N_NODES * HDIM * 4);
    unsigned short* P   = (unsigned short*)alloc((size_t)N_NODES * 512 * 2);
    unsigned short* Wp  = (unsigned short*)alloc((size_t)NLAYERS * 512 * 128 * 2);
    float* wfe          = (float*)alloc((size_t)NLAYERS * 128 * 4);
    float* wse          = (float*)alloc((size_t)NLAYERS * 128 * 4);
    int* deg            = (int*)alloc((size_t)N_NODES * 4);
    int* rowptr         = (int*)alloc((size_t)(N_NODES + 1) * 4);
    int* cursor         = (int*)alloc((size_t)N_NODES * 4);
    int* gstart         = (int*)alloc((size_t)(N_GRAPH + 1) * 4);
    int2* csr           = (int2*)alloc((size_t)N_EDGES * 8);

    hipMemsetAsync(deg, 0, (size_t)N_NODES * 4, stream);

    k_embed<<<(N_NODES * 32 + 255) / 256, 256, 0, stream>>>(atoms, embed, x);
    k_hist<<<(N_EDGES + 255) / 256, 256, 0, stream>>>(ei, deg);
    k_scan<<<1, 1024, 0, stream>>>(deg, rowptr, cursor);
    k_scatter<<<(N_EDGES + 255) / 256, 256, 0, stream>>>(ei, pos, cursor, csr);
    k_gbound<<<2, 256, 0, stream>>>(batch, gstart);
    k_pack<<<dim3(257, NLAYERS), 256, 0, stream>>>(lin_f_w, lin_s_w, Wp, wfe, wse);

    for (int l = 0; l < NLAYERS; ++l) {
        k_gemm<<<dim3(625, 2), 512, 0, stream>>>(x, Wp + (size_t)l * 512 * 128,
                                                 lin_f_b + (size_t)l * HDIM,
                                                 lin_s_b + (size_t)l * HDIM, P);
        k_edge_csr<<<N_NODES / 4, 256, 0, stream>>>(P, wfe + (size_t)l * 128,
                                                    wse + (size_t)l * 128, rowptr, csr, x);
    }

    k_poolfc<<<N_GRAPH, 128, 0, stream>>>(x, gstart, fc_w, fc_b, out_w, out_b, out);
}